// Round 10
// baseline (50.511 us; speedup 1.0000x reference)
//
#include <hip/hip_runtime.h>
#include <hip/hip_bf16.h>
#include <cstdint>

// Problem constants (N read from in_sizes at launch; C, D fixed by reference).
#define DIM 64
#define NC  1024
#define PF  2   // register-pipeline depth (tiles in flight)

typedef __attribute__((ext_vector_type(8)))  __bf16 bf16x8;
typedef __attribute__((ext_vector_type(8)))  short  short8;
typedef __attribute__((ext_vector_type(16))) float  f32x16;
typedef __attribute__((ext_vector_type(4)))  unsigned int uint4v;

static __device__ __forceinline__ unsigned short f32_to_bf16_rne(float f) {
    unsigned int u = __builtin_bit_cast(unsigned int, f);
    unsigned int r = u + 0x7FFFu + ((u >> 16) & 1u);
    return (unsigned short)(r >> 16);
}
static __device__ __forceinline__ float bf16_bits_to_f32(unsigned short h) {
    return __builtin_bit_cast(float, (unsigned int)h << 16);
}

// ---------------------------------------------------------------------------
// Prep 1: normalized |coefs| weights -> wc2[c].x    (1 block, 1024 threads)
// ---------------------------------------------------------------------------
__global__ void coef_kernel(const float* __restrict__ coefs,
                            float2* __restrict__ wc2) {
    __shared__ float red[NC];
    const int c = threadIdx.x;
    const float a = fabsf(coefs[c]);
    red[c] = a;
    __syncthreads();
    for (int s = NC / 2; s > 0; s >>= 1) {
        if (c < s) red[c] += red[c + s];
        __syncthreads();
    }
    const float sum = red[0];
    const float w = (sum == 0.0f) ? a : a / sum;
    wc2[c].x = w;
}

// ---------------------------------------------------------------------------
// Prep 2: per-center c2 as a bf16 (hi, residual) pair packed in wc2[c].y;
// bf16(-2*centers) in 32x32x16 MFMA B-fragment layout -> bfrag.
// Grid: NC/64 blocks x 64 threads, one center per thread.
//
// B-fragment layout for mfma_f32_32x32x16_bf16 (K-step ks = 0..3):
//   lane supplies B[k][col], col = lane&31, k = ks*16 + (lane>>5)*8 + j.
//   Stored as bfrag[(tile*4 + ks)*64 + (h*32 + col)] : short8, h = k-half.
// ---------------------------------------------------------------------------
__global__ void center_kernel(const float* __restrict__ centers,
                              float2* __restrict__ wc2,
                              short8* __restrict__ bfrag) {
    const int c = blockIdx.x * 64 + threadIdx.x;
    const float4* row = (const float4*)(centers + (size_t)c * DIM);

    float vals[DIM];
    float c2 = 0.0f;
#pragma unroll
    for (int q = 0; q < DIM / 4; ++q) {
        float4 v = row[q];
        vals[q * 4 + 0] = v.x; vals[q * 4 + 1] = v.y;
        vals[q * 4 + 2] = v.z; vals[q * 4 + 3] = v.w;
        c2 = fmaf(v.x, v.x, c2); c2 = fmaf(v.y, v.y, c2);
        c2 = fmaf(v.z, v.z, c2); c2 = fmaf(v.w, v.w, c2);
    }
    // hi + residual bf16 split (k=0 slot carries hi, k=1 slot carries lo).
    const unsigned short hi = f32_to_bf16_rne(c2);
    const unsigned short lo = f32_to_bf16_rne(c2 - bf16_bits_to_f32(hi));
    const unsigned int packed = (unsigned int)hi | ((unsigned int)lo << 16);
    wc2[c].y = __builtin_bit_cast(float, packed);

    const int tile = c >> 5;
    const int col  = c & 31;
#pragma unroll
    for (int ks = 0; ks < 4; ++ks) {
#pragma unroll
        for (int h = 0; h < 2; ++h) {
            short8 p;
#pragma unroll
            for (int j = 0; j < 8; ++j) {
                float v = -2.0f * vals[ks * 16 + h * 8 + j];
                p[j] = (short)f32_to_bf16_rne(v);
            }
            bfrag[(tile * 4 + ks) * 64 + (h * 32 + col)] = p;
        }
    }
}

// ---------------------------------------------------------------------------
// Main: block = 256 threads = 4 waves, block owns 64 rows + full C.
//   wave w: rg = w>>1 owns rows [R + rg*32, +32) as ONE 32x32 fragment set;
//           half = w&1 owns a 512-center half (16 tiles of 32 centers).
// 32x32x16 shape: one tile = 1024 outputs for 5 MFMA + 4 B-loads (vs 12
// MFMA + 8 loads on the 16x16 path) -> ~3x fewer issued instructions per
// output (r9 post-mortem: per-tile instruction overhead is the bottleneck).
// Per tile t (32 centers):
//   acc = mfma32(ones[k=0,1], bc2(t), C = x2init)   // acc = x2 + c2
//   acc = mfma32(A[ks], B[ks](t), acc), ks=0..3     // acc = d^2
//   epilogue: d = sqrt(|acc|); sum[r] = fma(w_col, d, sum[r])
// C/D layout (HW-verified m74/m101): col=lane&31, row=(reg&3)+8*(reg>>2)
// +4*(lane>>5). Final: xor-shuffle reduce over 32 cols, LDS-combine the two
// halves per row-group, write 64 rows.
// ---------------------------------------------------------------------------
__global__ __launch_bounds__(256, 4) void dist_kernel(
    const float* __restrict__ x,
    const float2* __restrict__ wc2,
    const bf16x8* __restrict__ bfrag,
    const float* __restrict__ madp,
    float* __restrict__ out)
{
    const int lane = threadIdx.x & 63;
    const int wave = threadIdx.x >> 6;
    const int col  = lane & 31;        // output column within tile
    const int kh   = lane >> 5;        // k-half selector
    const int rg   = wave >> 1;        // row-group (32 rows)
    const int half = wave & 1;         // center-half selector
    const int R = blockIdx.x * 64;

    __shared__ float x2lds[4][32];     // wave-local x2 broadcast
    __shared__ float part[4][32];

    // ---- Prologue: load this wave's 32 rows, build A-frags + x2.
    // lane: row = R + rg*32 + col, k-slice = ks*16 + kh*8 .. +7.
    bf16x8 afrag[4];
    float s2 = 0.0f;
    {
        const int row = R + rg * 32 + col;
        const float* rp = x + (size_t)row * DIM + kh * 8;
#pragma unroll
        for (int ks = 0; ks < 4; ++ks) {
            float4 v0 = *(const float4*)(rp + ks * 16);
            float4 v1 = *(const float4*)(rp + ks * 16 + 4);
            float vv[8] = {v0.x, v0.y, v0.z, v0.w, v1.x, v1.y, v1.z, v1.w};
            short8 p;
#pragma unroll
            for (int j = 0; j < 8; ++j) {
                s2 = fmaf(vv[j], vv[j], s2);
                p[j] = (short)f32_to_bf16_rne(vv[j]);
            }
            afrag[ks] = __builtin_bit_cast(bf16x8, p);
        }
        // lane holds 32 of row's 64 values; combine the two k-halves.
        s2 += __shfl_xor(s2, 32, 64);
        // Wave-local broadcast via LDS (no barrier needed: same wave).
        if (kh == 0) x2lds[wave][col] = s2;
    }
    // x2 in accumulator layout: row(reg) = (reg&3)+8*(reg>>2)+4*kh.
    f32x16 x2init;
#pragma unroll
    for (int reg = 0; reg < 16; ++reg)
        x2init[reg] = x2lds[wave][(reg & 3) + 8 * (reg >> 2) + 4 * kh];

    // Constant A fragment [1,1,0,...]: k=0,1 live in kh==0 lanes, j=0,1.
    const unsigned int ao = (kh == 0) ? 0x3F803F80u : 0u;
    const bf16x8 afones = __builtin_bit_cast(bf16x8, (uint4v){ao, 0u, 0u, 0u});

    float sum[16];
#pragma unroll
    for (int r = 0; r < 16; ++r) sum[r] = 0.0f;

    const int tbase = half * 16;         // 16 tiles of 32 centers
    const bf16x8* bp = bfrag + lane;     // lane-fixed base
    const float2* wp = wc2 + col;

    // Fill the register pipeline: slots j = tiles tbase+j.
    bf16x8 pb[PF][4];
    float2 pwc[PF];
#pragma unroll
    for (int j = 0; j < PF; ++j) {
        const int t = tbase + j;
#pragma unroll
        for (int ks = 0; ks < 4; ++ks) pb[j][ks] = bp[(t * 4 + ks) * 64];
        pwc[j] = wp[t * 32];
    }

#pragma unroll 1   // MUST stay rolled (round 6: full unroll -> spill)
    for (int i = 0; i < 16; i += PF) {
#pragma unroll
        for (int j = 0; j < PF; ++j) {
            const float2 wc = pwc[j];
            const float w = wc.x;
            const unsigned int packed = __builtin_bit_cast(unsigned int, wc.y);
            const bf16x8 bc2 = __builtin_bit_cast(bf16x8,
                (uint4v){(kh == 0) ? packed : 0u, 0u, 0u, 0u});
            bf16x8 b0 = pb[j][0], b1 = pb[j][1], b2 = pb[j][2], b3 = pb[j][3];

            // Prefetch tile i+j+PF into slot j (wrap at tail; harmless).
            {
                const int nxt = i + j + PF;
                const int tn = tbase + ((nxt < 16) ? nxt : 0);
#pragma unroll
                for (int ks = 0; ks < 4; ++ks) pb[j][ks] = bp[(tn * 4 + ks) * 64];
                pwc[j] = wp[tn * 32];
            }

            f32x16 acc;
            acc = __builtin_amdgcn_mfma_f32_32x32x16_bf16(afones, bc2, x2init, 0, 0, 0);
            acc = __builtin_amdgcn_mfma_f32_32x32x16_bf16(afrag[0], b0, acc, 0, 0, 0);
            acc = __builtin_amdgcn_mfma_f32_32x32x16_bf16(afrag[1], b1, acc, 0, 0, 0);
            acc = __builtin_amdgcn_mfma_f32_32x32x16_bf16(afrag[2], b2, acc, 0, 0, 0);
            acc = __builtin_amdgcn_mfma_f32_32x32x16_bf16(afrag[3], b3, acc, 0, 0, 0);

#pragma unroll
            for (int r = 0; r < 16; ++r) {
                float d = __builtin_amdgcn_sqrtf(fabsf(acc[r]));
                sum[r] = fmaf(w, d, sum[r]);
            }
        }
    }

    // Reduce over the 32 col-lanes (xor masks stay within a 32-group).
#pragma unroll
    for (int reg = 0; reg < 16; ++reg) {
        float v = sum[reg];
        v += __shfl_xor(v, 1, 64);
        v += __shfl_xor(v, 2, 64);
        v += __shfl_xor(v, 4, 64);
        v += __shfl_xor(v, 8, 64);
        v += __shfl_xor(v, 16, 64);
        if (col == 0)
            part[wave][(reg & 3) + 8 * (reg >> 2) + 4 * kh] = v;
    }
    __syncthreads();

    // Combine the two center-halves per row-group and write 64 rows.
    const int tid = threadIdx.x;
    if (tid < 64) {
        const int r2 = tid >> 5;       // row-group
        const int r  = tid & 31;       // row within group
        const float s = part[r2 * 2][r] + part[r2 * 2 + 1][r];
        out[R + r2 * 32 + r] = madp[0] - s;
    }
}

extern "C" void kernel_launch(void* const* d_in, const int* in_sizes, int n_in,
                              void* d_out, int out_size, void* d_ws, size_t ws_size,
                              hipStream_t stream) {
    const float* x       = (const float*)d_in[0];
    const float* centers = (const float*)d_in[1];
    const float* coefs   = (const float*)d_in[2];
    const float* mad     = (const float*)d_in[3];
    float* out = (float*)d_out;

    float2* wc2   = (float2*)d_ws;
    short8* bfrag = (short8*)((char*)d_ws + NC * sizeof(float2));

    const int N = in_sizes[0] / DIM;

    coef_kernel<<<1, NC, 0, stream>>>(coefs, wc2);
    center_kernel<<<NC / 64, 64, 0, stream>>>(centers, wc2, bfrag);
    dist_kernel<<<N / 64, 256, 0, stream>>>(x, wc2, (const bf16x8*)bfrag, mad, out);
}

// Round 11
// 46.351 us; speedup vs baseline: 1.0897x; 1.0897x over previous
//
#include <hip/hip_runtime.h>
#include <hip/hip_bf16.h>
#include <cstdint>

// Problem constants (N read from in_sizes at launch; C, D fixed by reference).
#define DIM 64
#define NC  1024

typedef __attribute__((ext_vector_type(8))) __bf16 bf16x8;
typedef __attribute__((ext_vector_type(8))) short short8;
typedef __attribute__((ext_vector_type(4))) float f32x4;

static __device__ __forceinline__ unsigned short f32_to_bf16_rne(float f) {
    unsigned int u = __builtin_bit_cast(unsigned int, f);
    unsigned int r = u + 0x7FFFu + ((u >> 16) & 1u);
    return (unsigned short)(r >> 16);
}

// ---------------------------------------------------------------------------
// Prep 1: normalized |coefs| weights -> wc2[c].x    (1 block, 1024 threads)
// ---------------------------------------------------------------------------
__global__ void coef_kernel(const float* __restrict__ coefs,
                            float2* __restrict__ wc2) {
    __shared__ float red[NC];
    const int c = threadIdx.x;
    const float a = fabsf(coefs[c]);
    red[c] = a;
    __syncthreads();
    for (int s = NC / 2; s > 0; s >>= 1) {
        if (c < s) red[c] += red[c + s];
        __syncthreads();
    }
    const float sum = red[0];
    const float w = (sum == 0.0f) ? a : a / sum;
    wc2[c].x = w;
}

// ---------------------------------------------------------------------------
// Prep 2: center norms -> wc2[c].y (plain f32); bf16(-2*centers) in MFMA
// B-fragment layout -> bfrag.  Grid: NC/64 blocks x 64 threads.
//
// B-fragment layout for mfma_f32_16x16x32_bf16:
//   lane supplies B[k][col] with col = lane&15, k = (lane>>4)*8 + j.
//   Stored as bfrag[(tile*2 + kb)*64 + lane] : short8 (16B per lane).
// ---------------------------------------------------------------------------
__global__ void center_kernel(const float* __restrict__ centers,
                              float2* __restrict__ wc2,
                              short8* __restrict__ bfrag) {
    const int c = blockIdx.x * 64 + threadIdx.x;
    const float4* row = (const float4*)(centers + (size_t)c * DIM);

    float vals[DIM];
    float c2 = 0.0f;
#pragma unroll
    for (int q = 0; q < DIM / 4; ++q) {
        float4 v = row[q];
        vals[q * 4 + 0] = v.x; vals[q * 4 + 1] = v.y;
        vals[q * 4 + 2] = v.z; vals[q * 4 + 3] = v.w;
        c2 = fmaf(v.x, v.x, c2); c2 = fmaf(v.y, v.y, c2);
        c2 = fmaf(v.z, v.z, c2); c2 = fmaf(v.w, v.w, c2);
    }
    wc2[c].y = c2;

    const int tile = c >> 4;
    const int colL = c & 15;
#pragma unroll
    for (int kb = 0; kb < 2; ++kb) {
#pragma unroll
        for (int h = 0; h < 4; ++h) {
            short8 p;
#pragma unroll
            for (int j = 0; j < 8; ++j) {
                float v = -2.0f * vals[kb * 32 + h * 8 + j];
                p[j] = (short)f32_to_bf16_rne(v);
            }
            bfrag[(tile * 2 + kb) * 64 + (h * 16 + colL)] = p;
        }
    }
}

// ---------------------------------------------------------------------------
// Main (r4 champion structure + explicit 2-tile ILP interleave):
// block = 256 threads = 4 waves = 2 wave-pairs.
//   Wave pair p owns rows [blockBase + p*64, +64); wave parity owns a
//   512-center half (32 tiles of 16).
// r10 post-mortem: kernel is LATENCY-bound at ~3 waves/SIMD — serial
// acc->acc MFMA chains + sqrt chains run at latency, not throughput.
// Fix: per outer iteration process TWO tiles fully interleaved -> 8
// independent 2-deep MFMA chains (was 4x3-deep), epilogues overlap the
// other tile's MFMAs. acc init back to VALU adds (plain f32 c2) — off
// the matrix-pipe critical chain, schedulable early.
// Keep: launch_bounds(256,4) [r4-proven codegen], outer loop pinned
// rolled [r6 spill lesson], PF=2 register pipeline.
// ---------------------------------------------------------------------------
__global__ __launch_bounds__(256, 4) void dist_kernel(
    const float* __restrict__ x,
    const float2* __restrict__ wc2,
    const bf16x8* __restrict__ bfrag,
    const float* __restrict__ madp,
    float* __restrict__ out)
{
    const int lane = threadIdx.x & 63;
    const int wave = threadIdx.x >> 6;
    const int lo = lane & 15;
    const int hi = lane >> 4;
    const int pairIdx = wave >> 1;     // which 64-row group of the block
    const int halfC  = wave & 1;       // which 512-center half
    const int rowBase = blockIdx.x * 128 + pairIdx * 64;

    __shared__ float part[4][64];

    bf16x8 afrag[4][2];
    float x2v[4][4];

    // Prologue: load A rows, convert to bf16 fragments, compute x2 per row.
#pragma unroll
    for (int g = 0; g < 4; ++g) {
        const int row = rowBase + g * 16 + lo;
        const float* rp = x + (size_t)row * DIM + hi * 8;
        float s2 = 0.0f;
#pragma unroll
        for (int kb = 0; kb < 2; ++kb) {
            float4 v0 = *(const float4*)(rp + kb * 32);
            float4 v1 = *(const float4*)(rp + kb * 32 + 4);
            float vv[8] = {v0.x, v0.y, v0.z, v0.w, v1.x, v1.y, v1.z, v1.w};
            short8 p;
#pragma unroll
            for (int j = 0; j < 8; ++j) {
                s2 = fmaf(vv[j], vv[j], s2);
                p[j] = (short)f32_to_bf16_rne(vv[j]);
            }
            afrag[g][kb] = __builtin_bit_cast(bf16x8, p);
        }
        // lane holds 16 of row's 64 values; combine the 4 hi-groups.
        s2 += __shfl_xor(s2, 16, 64);
        s2 += __shfl_xor(s2, 32, 64);
        // Redistribute to accumulator layout (acc elem b <-> row g*16+hi*4+b).
#pragma unroll
        for (int b = 0; b < 4; ++b)
            x2v[g][b] = __shfl(s2, hi * 4 + b, 64);
    }

    float sum[4][4];
#pragma unroll
    for (int g = 0; g < 4; ++g)
#pragma unroll
        for (int b = 0; b < 4; ++b) sum[g][b] = 0.0f;

    const int tbase = halfC * 32;
    const bf16x8* bp = bfrag + lane;     // lane-fixed base
    const float2* wp = wc2 + lo;

    // Fill the 2-slot pipeline: slot s = tile tbase+s.
    bf16x8 pb0[2], pb1[2];
    float2 pwc[2];
#pragma unroll
    for (int s = 0; s < 2; ++s) {
        const int t = tbase + s;
        pb0[s] = bp[t * 128];
        pb1[s] = bp[t * 128 + 64];
        pwc[s] = wp[t * 16];
    }

#pragma unroll 1   // MUST stay rolled (round 6: full unroll -> spill)
    for (int i = 0; i < 32; i += 2) {
        // Capture both tiles' operands.
        const float2 wcA = pwc[0], wcB = pwc[1];
        const bf16x8 a00 = pb0[0], a01 = pb1[0];
        const bf16x8 a10 = pb0[1], a11 = pb1[1];

        // Prefetch tiles i+2, i+3 into the slots (wrap at tail; harmless).
        {
            const int n0 = i + 2, n1 = i + 3;
            const int t0 = tbase + ((n0 < 32) ? n0 : 0);
            const int t1 = tbase + ((n1 < 32) ? n1 : 0);
            pb0[0] = bp[t0 * 128]; pb1[0] = bp[t0 * 128 + 64]; pwc[0] = wp[t0 * 16];
            pb0[1] = bp[t1 * 128]; pb1[1] = bp[t1 * 128 + 64]; pwc[1] = wp[t1 * 16];
        }

        // acc init on VALU (independent of matrix pipe, schedulable early).
        f32x4 acc0[4], acc1[4];
#pragma unroll
        for (int g = 0; g < 4; ++g)
#pragma unroll
            for (int b = 0; b < 4; ++b) {
                acc0[g][b] = x2v[g][b] + wcA.y;
                acc1[g][b] = x2v[g][b] + wcB.y;
            }

        // 8 independent 2-deep MFMA chains, interleaved across the 2 tiles.
#pragma unroll
        for (int g = 0; g < 4; ++g)
            acc0[g] = __builtin_amdgcn_mfma_f32_16x16x32_bf16(afrag[g][0], a00, acc0[g], 0, 0, 0);
#pragma unroll
        for (int g = 0; g < 4; ++g)
            acc1[g] = __builtin_amdgcn_mfma_f32_16x16x32_bf16(afrag[g][0], a10, acc1[g], 0, 0, 0);
#pragma unroll
        for (int g = 0; g < 4; ++g)
            acc0[g] = __builtin_amdgcn_mfma_f32_16x16x32_bf16(afrag[g][1], a01, acc0[g], 0, 0, 0);
#pragma unroll
        for (int g = 0; g < 4; ++g)
            acc1[g] = __builtin_amdgcn_mfma_f32_16x16x32_bf16(afrag[g][1], a11, acc1[g], 0, 0, 0);

        // Epilogues (trans+VALU pipes; overlap the other tile's MFMAs).
#pragma unroll
        for (int g = 0; g < 4; ++g)
#pragma unroll
            for (int b = 0; b < 4; ++b) {
                float d = __builtin_amdgcn_sqrtf(fabsf(acc0[g][b]));
                sum[g][b] = fmaf(wcA.x, d, sum[g][b]);
            }
#pragma unroll
        for (int g = 0; g < 4; ++g)
#pragma unroll
            for (int b = 0; b < 4; ++b) {
                float d = __builtin_amdgcn_sqrtf(fabsf(acc1[g][b]));
                sum[g][b] = fmaf(wcB.x, d, sum[g][b]);
            }
    }

    // Reduce over the 16 col-lanes of this wave's half, park in LDS.
#pragma unroll
    for (int g = 0; g < 4; ++g) {
#pragma unroll
        for (int b = 0; b < 4; ++b) {
            float v = sum[g][b];
            v += __shfl_xor(v, 1, 64);
            v += __shfl_xor(v, 2, 64);
            v += __shfl_xor(v, 4, 64);
            v += __shfl_xor(v, 8, 64);
            if (lo == 0) part[wave][g * 16 + hi * 4 + b] = v;
        }
    }
    __syncthreads();

    // Combine the two center-halves and write 128 rows.
    const int tid = threadIdx.x;
    if (tid < 128) {
        const int p = tid >> 6;
        const int r = tid & 63;
        const float s = part[2 * p][r] + part[2 * p + 1][r];
        out[blockIdx.x * 128 + p * 64 + r] = madp[0] - s;
    }
}

extern "C" void kernel_launch(void* const* d_in, const int* in_sizes, int n_in,
                              void* d_out, int out_size, void* d_ws, size_t ws_size,
                              hipStream_t stream) {
    const float* x       = (const float*)d_in[0];
    const float* centers = (const float*)d_in[1];
    const float* coefs   = (const float*)d_in[2];
    const float* mad     = (const float*)d_in[3];
    float* out = (float*)d_out;

    float2* wc2   = (float2*)d_ws;
    short8* bfrag = (short8*)((char*)d_ws + NC * sizeof(float2));

    const int N = in_sizes[0] / DIM;

    coef_kernel<<<1, NC, 0, stream>>>(coefs, wc2);
    center_kernel<<<NC / 64, 64, 0, stream>>>(centers, wc2, bfrag);
    dist_kernel<<<N / 128, 256, 0, stream>>>(x, wc2, (const bf16x8*)bfrag, mad, out);
}

// Round 13
// 45.163 us; speedup vs baseline: 1.1184x; 1.0263x over previous
//
#include <hip/hip_runtime.h>
#include <hip/hip_bf16.h>
#include <cstdint>

// Problem constants (N read from in_sizes at launch; C, D fixed by reference).
#define DIM 64
#define NC  1024

typedef __attribute__((ext_vector_type(8))) __bf16 bf16x8;
typedef __attribute__((ext_vector_type(8))) short short8;
typedef __attribute__((ext_vector_type(4))) float f32x4;

static __device__ __forceinline__ unsigned short f32_to_bf16_rne(float f) {
    unsigned int u = __builtin_bit_cast(unsigned int, f);
    unsigned int r = u + 0x7FFFu + ((u >> 16) & 1u);
    return (unsigned short)(r >> 16);
}

// ---------------------------------------------------------------------------
// Prep 1: normalized |coefs| weights -> wc2[c].x    (1 block, 1024 threads)
// ---------------------------------------------------------------------------
__global__ void coef_kernel(const float* __restrict__ coefs,
                            float2* __restrict__ wc2) {
    __shared__ float red[NC];
    const int c = threadIdx.x;
    const float a = fabsf(coefs[c]);
    red[c] = a;
    __syncthreads();
    for (int s = NC / 2; s > 0; s >>= 1) {
        if (c < s) red[c] += red[c + s];
        __syncthreads();
    }
    const float sum = red[0];
    const float w = (sum == 0.0f) ? a : a / sum;
    wc2[c].x = w;
}

// ---------------------------------------------------------------------------
// Prep 2: center norms -> wc2[c].y (plain f32); bf16(-2*centers) in MFMA
// B-fragment layout -> bfrag.  Grid: NC/64 blocks x 64 threads.
//
// B-fragment layout for mfma_f32_16x16x32_bf16:
//   lane supplies B[k][col] with col = lane&15, k = (lane>>4)*8 + j.
//   Stored as bfrag[(tile*2 + kb)*64 + lane] : short8 (16B per lane).
// ---------------------------------------------------------------------------
__global__ void center_kernel(const float* __restrict__ centers,
                              float2* __restrict__ wc2,
                              short8* __restrict__ bfrag) {
    const int c = blockIdx.x * 64 + threadIdx.x;
    const float4* row = (const float4*)(centers + (size_t)c * DIM);

    float vals[DIM];
    float c2 = 0.0f;
#pragma unroll
    for (int q = 0; q < DIM / 4; ++q) {
        float4 v = row[q];
        vals[q * 4 + 0] = v.x; vals[q * 4 + 1] = v.y;
        vals[q * 4 + 2] = v.z; vals[q * 4 + 3] = v.w;
        c2 = fmaf(v.x, v.x, c2); c2 = fmaf(v.y, v.y, c2);
        c2 = fmaf(v.z, v.z, c2); c2 = fmaf(v.w, v.w, c2);
    }
    wc2[c].y = c2;

    const int tile = c >> 4;
    const int colL = c & 15;
#pragma unroll
    for (int kb = 0; kb < 2; ++kb) {
#pragma unroll
        for (int h = 0; h < 4; ++h) {
            short8 p;
#pragma unroll
            for (int j = 0; j < 8; ++j) {
                float v = -2.0f * vals[kb * 32 + h * 8 + j];
                p[j] = (short)f32_to_bf16_rne(v);
            }
            bfrag[(tile * 2 + kb) * 64 + (h * 16 + colL)] = p;
        }
    }
}

// ---------------------------------------------------------------------------
// Main (r11 structure, ONE change: x loads + out store are NONTEMPORAL).
// Theory: x streaming (33.5 MB) thrashes the 4 MB per-XCD L2 and evicts the
// 128 KB bfrag working set -> B loads pay L3-class latency (~600-1000 cyc),
// overrunning the PF=2 prefetch lead (~500 cyc) -> the ~1000 cyc/iter
// unfilled stall that has pinned every structure at ~41-45 us. NT hints keep
// x out of L2 retention; bfrag+wc2 (136 KB) stay L2-hot; B-load latency
// drops to L2-hit (~200 cyc), covered by the existing prefetch.
// block = 256 threads = 4 waves = 2 wave-pairs.
//   Wave pair p owns rows [blockBase + p*64, +64); wave parity owns a
//   512-center half (32 tiles of 16).
// Keep: launch_bounds(256,4) [r4-proven codegen], outer loop pinned rolled
// [r6 spill lesson], PF=2 slots, 2-tile interleave, VALU acc-init.
// NOTE: __builtin_nontemporal_load needs a clang ext-vector pointer, not
// HIP_vector_type (r12 compile fail) — hence f32x4 here.
// ---------------------------------------------------------------------------
__global__ __launch_bounds__(256, 4) void dist_kernel(
    const float* __restrict__ x,
    const float2* __restrict__ wc2,
    const bf16x8* __restrict__ bfrag,
    const float* __restrict__ madp,
    float* __restrict__ out)
{
    const int lane = threadIdx.x & 63;
    const int wave = threadIdx.x >> 6;
    const int lo = lane & 15;
    const int hi = lane >> 4;
    const int pairIdx = wave >> 1;     // which 64-row group of the block
    const int halfC  = wave & 1;       // which 512-center half
    const int rowBase = blockIdx.x * 128 + pairIdx * 64;

    __shared__ float part[4][64];

    bf16x8 afrag[4][2];
    float x2v[4][4];

    // Prologue: load A rows (NONTEMPORAL — single-use stream, keep out of
    // L2), convert to bf16 fragments, compute x2 per row.
#pragma unroll
    for (int g = 0; g < 4; ++g) {
        const int row = rowBase + g * 16 + lo;
        const float* rp = x + (size_t)row * DIM + hi * 8;
        float s2 = 0.0f;
#pragma unroll
        for (int kb = 0; kb < 2; ++kb) {
            f32x4 v0 = __builtin_nontemporal_load((const f32x4*)(rp + kb * 32));
            f32x4 v1 = __builtin_nontemporal_load((const f32x4*)(rp + kb * 32 + 4));
            float vv[8] = {v0.x, v0.y, v0.z, v0.w, v1.x, v1.y, v1.z, v1.w};
            short8 p;
#pragma unroll
            for (int j = 0; j < 8; ++j) {
                s2 = fmaf(vv[j], vv[j], s2);
                p[j] = (short)f32_to_bf16_rne(vv[j]);
            }
            afrag[g][kb] = __builtin_bit_cast(bf16x8, p);
        }
        // lane holds 16 of row's 64 values; combine the 4 hi-groups.
        s2 += __shfl_xor(s2, 16, 64);
        s2 += __shfl_xor(s2, 32, 64);
        // Redistribute to accumulator layout (acc elem b <-> row g*16+hi*4+b).
#pragma unroll
        for (int b = 0; b < 4; ++b)
            x2v[g][b] = __shfl(s2, hi * 4 + b, 64);
    }

    float sum[4][4];
#pragma unroll
    for (int g = 0; g < 4; ++g)
#pragma unroll
        for (int b = 0; b < 4; ++b) sum[g][b] = 0.0f;

    const int tbase = halfC * 32;
    const bf16x8* bp = bfrag + lane;     // lane-fixed base
    const float2* wp = wc2 + lo;

    // Fill the 2-slot pipeline: slot s = tile tbase+s.
    bf16x8 pb0[2], pb1[2];
    float2 pwc[2];
#pragma unroll
    for (int s = 0; s < 2; ++s) {
        const int t = tbase + s;
        pb0[s] = bp[t * 128];
        pb1[s] = bp[t * 128 + 64];
        pwc[s] = wp[t * 16];
    }

#pragma unroll 1   // MUST stay rolled (round 6: full unroll -> spill)
    for (int i = 0; i < 32; i += 2) {
        // Capture both tiles' operands.
        const float2 wcA = pwc[0], wcB = pwc[1];
        const bf16x8 a00 = pb0[0], a01 = pb1[0];
        const bf16x8 a10 = pb0[1], a11 = pb1[1];

        // Prefetch tiles i+2, i+3 into the slots (wrap at tail; harmless).
        {
            const int n0 = i + 2, n1 = i + 3;
            const int t0 = tbase + ((n0 < 32) ? n0 : 0);
            const int t1 = tbase + ((n1 < 32) ? n1 : 0);
            pb0[0] = bp[t0 * 128]; pb1[0] = bp[t0 * 128 + 64]; pwc[0] = wp[t0 * 16];
            pb0[1] = bp[t1 * 128]; pb1[1] = bp[t1 * 128 + 64]; pwc[1] = wp[t1 * 16];
        }

        // acc init on VALU (independent of matrix pipe, schedulable early).
        f32x4 acc0[4], acc1[4];
#pragma unroll
        for (int g = 0; g < 4; ++g)
#pragma unroll
            for (int b = 0; b < 4; ++b) {
                acc0[g][b] = x2v[g][b] + wcA.y;
                acc1[g][b] = x2v[g][b] + wcB.y;
            }

        // 8 independent 2-deep MFMA chains, interleaved across the 2 tiles.
#pragma unroll
        for (int g = 0; g < 4; ++g)
            acc0[g] = __builtin_amdgcn_mfma_f32_16x16x32_bf16(afrag[g][0], a00, acc0[g], 0, 0, 0);
#pragma unroll
        for (int g = 0; g < 4; ++g)
            acc1[g] = __builtin_amdgcn_mfma_f32_16x16x32_bf16(afrag[g][0], a10, acc1[g], 0, 0, 0);
#pragma unroll
        for (int g = 0; g < 4; ++g)
            acc0[g] = __builtin_amdgcn_mfma_f32_16x16x32_bf16(afrag[g][1], a01, acc0[g], 0, 0, 0);
#pragma unroll
        for (int g = 0; g < 4; ++g)
            acc1[g] = __builtin_amdgcn_mfma_f32_16x16x32_bf16(afrag[g][1], a11, acc1[g], 0, 0, 0);

        // Epilogues (trans+VALU pipes; overlap the other tile's MFMAs).
#pragma unroll
        for (int g = 0; g < 4; ++g)
#pragma unroll
            for (int b = 0; b < 4; ++b) {
                float d = __builtin_amdgcn_sqrtf(fabsf(acc0[g][b]));
                sum[g][b] = fmaf(wcA.x, d, sum[g][b]);
            }
#pragma unroll
        for (int g = 0; g < 4; ++g)
#pragma unroll
            for (int b = 0; b < 4; ++b) {
                float d = __builtin_amdgcn_sqrtf(fabsf(acc1[g][b]));
                sum[g][b] = fmaf(wcB.x, d, sum[g][b]);
            }
    }

    // Reduce over the 16 col-lanes of this wave's half, park in LDS.
#pragma unroll
    for (int g = 0; g < 4; ++g) {
#pragma unroll
        for (int b = 0; b < 4; ++b) {
            float v = sum[g][b];
            v += __shfl_xor(v, 1, 64);
            v += __shfl_xor(v, 2, 64);
            v += __shfl_xor(v, 4, 64);
            v += __shfl_xor(v, 8, 64);
            if (lo == 0) part[wave][g * 16 + hi * 4 + b] = v;
        }
    }
    __syncthreads();

    // Combine the two center-halves and write 128 rows (NT store —
    // out is write-once, never re-read).
    const int tid = threadIdx.x;
    if (tid < 128) {
        const int p = tid >> 6;
        const int r = tid & 63;
        const float s = part[2 * p][r] + part[2 * p + 1][r];
        __builtin_nontemporal_store(madp[0] - s, &out[blockIdx.x * 128 + p * 64 + r]);
    }
}

extern "C" void kernel_launch(void* const* d_in, const int* in_sizes, int n_in,
                              void* d_out, int out_size, void* d_ws, size_t ws_size,
                              hipStream_t stream) {
    const float* x       = (const float*)d_in[0];
    const float* centers = (const float*)d_in[1];
    const float* coefs   = (const float*)d_in[2];
    const float* mad     = (const float*)d_in[3];
    float* out = (float*)d_out;

    float2* wc2   = (float2*)d_ws;
    short8* bfrag = (short8*)((char*)d_ws + NC * sizeof(float2));

    const int N = in_sizes[0] / DIM;

    coef_kernel<<<1, NC, 0, stream>>>(coefs, wc2);
    center_kernel<<<NC / 64, 64, 0, stream>>>(centers, wc2, bfrag);
    dist_kernel<<<N / 128, 256, 0, stream>>>(x, wc2, (const bf16x8*)bfrag, mad, out);
}